// Round 6
// baseline (3551.705 us; speedup 1.0000x reference)
//
#include <hip/hip_runtime.h>
#include <hip/hip_bf16.h>
#include <hip/hip_fp16.h>
#include <stdint.h>

// Seq2Seq LSTM: B=4096, H=512, E=128, 32 enc + 32 dec steps, V_tgt=128.
// Round 16: BARRIER-FREE, LDS-FREE REGISTER GEMM.
// Evidence: R13 (vmcnt pipeline) null; R11/12/14 (manual sync) worse; R15
// early-exit saved less than active-fraction => the ~20us step body is
// sync/LDS-structural. At this tile shape LDS has no dedup value (A rows
// are wave-private; B is 4-way shared = L1's job), and the MFMA fragment
// layout is row-contiguous 16B/lane: a wave's fragment load = 16 fully-
// consumed 64B lines = perfectly coalesced DIRECT global load. So the
// k-loop is now: 12 global half8 loads + 16 MFMA per k-tile, no LDS, no
// barriers, no vmcnt(0) drains; waves stream independently; compiler
// software-pipelines across the whole K-loop.
// Same per-lane operand values + same MFMA order + same epilogue as R15
// -> bitwise identical output. Keeps R15's length-sorted encoder early-
// exit, float4 proj table, hfinal capture, slot ring, perm-scatter.

#define NB     4096
#define SSRC   32
#define STGT   32
#define NVSRC  96
#define NVTGT  128
#define ED     128
#define HD     512
#define G4     2048   // 4*HD
#define NBHD   ((size_t)NB * HD)

typedef __attribute__((ext_vector_type(8))) _Float16 half8;
typedef __attribute__((ext_vector_type(4))) float fx4;

__device__ __forceinline__ float sigf(float x) { return 1.0f / (1.0f + __expf(-x)); }
__device__ __forceinline__ float tanhfast(float x) { return 1.0f - 2.0f / (__expf(2.0f * x) + 1.0f); }

__global__ void convert_half(const float* __restrict__ src, int n, _Float16* __restrict__ dst) {
    int i = blockIdx.x * 256 + threadIdx.x;
    if (i < n) dst[i] = (_Float16)src[i];
}

// 32x32 LDS-tiled transpose: outT[c][r] = in[r][c]; both sides coalesced.
__global__ __launch_bounds__(256) void transpose_f32(
    const float* __restrict__ in, float* __restrict__ outT, int R, int C, int rtiles)
{
    __shared__ float ls[32][33];
    const int bx = (int)blockIdx.x % rtiles;     // r-tile
    const int by = (int)blockIdx.x / rtiles;     // c-tile
    const int tx = threadIdx.x & 31, ty = threadIdx.x >> 5;   // ty 0..7
    #pragma unroll
    for (int i = 0; i < 4; i++) {
        int rr = ty + i * 8;
        ls[rr][tx] = in[(size_t)(bx * 32 + rr) * C + by * 32 + tx];
    }
    __syncthreads();
    #pragma unroll
    for (int i = 0; i < 4; i++) {
        int rr = ty + i * 8;
        outT[(size_t)(by * 32 + rr) * R + bx * 32 + tx] = ls[tx][rr];
    }
}

// proj[v][hcol][gate] = emb[v,:]·Wih[g,:] + bih[g] + bhh[g]  (gate-contig)
// g = gate*HD + hcol in the original gate-major index space.
__global__ __launch_bounds__(256) void build_tables3(
    const float* __restrict__ emb, const float* __restrict__ WT,
    const float* __restrict__ bih, const float* __restrict__ bhh,
    float* __restrict__ proj)
{
    __shared__ float embL[8][ED];
    const int gc = (int)blockIdx.x & 7;
    const int vc = (int)blockIdx.x >> 3;
    const int g  = gc * 256 + threadIdx.x;
    for (int i = threadIdx.x; i < 8 * ED; i += 256)
        embL[i >> 7][i & (ED - 1)] = emb[(size_t)(vc * 8 + (i >> 7)) * ED + (i & (ED - 1))];
    __syncthreads();
    float acc[8] = {0, 0, 0, 0, 0, 0, 0, 0};
    for (int e = 0; e < ED; e++) {
        float w = WT[(size_t)e * G4 + g];
        #pragma unroll
        for (int v = 0; v < 8; v++) acc[v] += embL[v][e] * w;
    }
    float bb = bih[g] + bhh[g];
    const int gate = g >> 9, hcol = g & (HD - 1);
    #pragma unroll
    for (int v = 0; v < 8; v++)
        proj[(((size_t)(vc * 8 + v) * HD + hcol) << 2) + gate] = acc[v] + bb;
}

// Counting sort of rows by src length (keys 1..32). Single block.
__global__ __launch_bounds__(256) void sort_rows(
    const int* __restrict__ lens, int* __restrict__ perm,
    int* __restrict__ lens_s, int* __restrict__ maxlen)
{
    __shared__ int hist[33];
    __shared__ int base[33];
    const int tid = threadIdx.x;
    if (tid < 33) hist[tid] = 0;
    __syncthreads();
    for (int i = tid; i < NB; i += 256) atomicAdd(&hist[lens[i]], 1);
    __syncthreads();
    if (tid == 0) {
        int s = 0;
        for (int l = 1; l <= 32; l++) { base[l] = s; s += hist[l]; }
    }
    __syncthreads();
    for (int i = tid; i < NB; i += 256) {
        int l = lens[i];
        int pos = atomicAdd(&base[l], 1);
        perm[pos] = i;
        lens_s[pos] = l;
    }
    __syncthreads();
    if (tid < 32) maxlen[tid] = lens_s[tid * 128 + 127];
}

// seq_s[sorted_row][t] = seq[perm[sorted_row]][t], S=32.
__global__ __launch_bounds__(256) void gather_seq(
    const int* __restrict__ seq, const int* __restrict__ perm,
    int* __restrict__ seq_s)
{
    int i = (int)blockIdx.x * 256 + threadIdx.x;   // over NB*32
    int row = i >> 5, t = i & 31;
    seq_s[i] = seq[perm[row] * 32 + t];
}

// Gate GEMM, 128m x 64n (4 gates x 16 hcols) per block + fused cell
// epilogue. 1024 blocks, 4/CU. NO LDS, NO BARRIERS: fragments loaded
// directly global->VGPR (each half8 load = 16 fully-used 64B lines).
__global__ __launch_bounds__(256, 4) void lstm_step(
    const _Float16* __restrict__ h_r, _Float16* __restrict__ h_w,
    float* __restrict__ c_state,
    const float* __restrict__ proj,      // [tok][hcol][4]
    const int* __restrict__ seq_s, const int* __restrict__ lens_s,
    const int* __restrict__ maxlen,
    const _Float16* __restrict__ W,
    _Float16* __restrict__ hfinal,
    int t, int is_enc, int skip_gemm)
{
    const int tid = threadIdx.x;
    const int lane = tid & 63;
    const int wid  = tid >> 6;
    const int wm   = wid * 32;                     // wave m-offset (0..96)
    const int quad = lane >> 4;
    const int l15  = lane & 15;

    // XCD swizzle: per-XCD ws = 16 m-tiles + 8 hcol-tiles
    const int x = (int)blockIdx.x & 7, j = (int)blockIdx.x >> 3;
    const int mt = (x & 1) * 16 + (j & 15);            // m-tile (sorted space)
    const int m0 = mt * 128;
    const int c0 = ((x >> 1) * 8 + (j >> 4)) * 16;     // hcol tile (32 total)

    // whole tile frozen: finals already in hfinal/c_state
    if (is_enc && t >= maxlen[mt]) return;

    // Fragment source pointers (include quad*8 k-offset).
    // A: row m0+wm+mf*16+l15, k = k0+kk+quad*8
    // B: row g*HD + c0 + l15 of W, same k pattern
    const _Float16* arow[2];
    #pragma unroll
    for (int mf = 0; mf < 2; mf++)
        arow[mf] = h_r + (size_t)(m0 + wm + mf * 16 + l15) * HD + quad * 8;
    const _Float16* brow[4];
    #pragma unroll
    for (int g = 0; g < 4; g++)
        brow[g] = W + (size_t)(g * HD + c0 + l15) * HD + quad * 8;

    fx4 acc[2][4];
    #pragma unroll
    for (int i = 0; i < 2; i++)
        #pragma unroll
        for (int jj = 0; jj < 4; jj++)
            acc[i][jj] = fx4{0.f, 0.f, 0.f, 0.f};

    if (!skip_gemm) {
        for (int k0 = 0; k0 < HD; k0 += 64) {
            #pragma unroll
            for (int kk = 0; kk < 64; kk += 32) {
                half8 af[2], bf[4];
                #pragma unroll
                for (int mf = 0; mf < 2; mf++)
                    af[mf] = *(const half8*)(arow[mf] + k0 + kk);
                #pragma unroll
                for (int g = 0; g < 4; g++)
                    bf[g] = *(const half8*)(brow[g] + k0 + kk);
                #pragma unroll
                for (int mf = 0; mf < 2; mf++)
                    #pragma unroll
                    for (int g = 0; g < 4; g++)
                        acc[mf][g] = __builtin_amdgcn_mfma_f32_16x16x32_f16(
                            af[mf], bf[g], acc[mf][g], 0, 0, 0);
            }
        }
    }

    // fused cell epilogue: acc[mf][gate][r] — all 4 gates per (row,hcol)
    const int hcol = c0 + l15;
    #pragma unroll
    for (int mf = 0; mf < 2; mf++) {
        #pragma unroll
        for (int r = 0; r < 4; r++) {
            int row = m0 + wm + mf * 16 + quad * 4 + r;
            int tok = is_enc ? seq_s[row * SSRC + t]
                             : (t == 0 ? 1 : seq_s[row * STGT + t - 1]);  // SOS=1
            const fx4 xp = *(const fx4*)&proj[((size_t)tok * HD + hcol) << 2];
            float gi = acc[mf][0][r] + xp[0];
            float gf = acc[mf][1][r] + xp[1];
            float gg = acc[mf][2][r] + xp[2];
            float go = acc[mf][3][r] + xp[3];
            float ii = sigf(gi), ff = sigf(gf), oo = sigf(go);
            float g2 = tanhfast(gg);
            size_t off = (size_t)row * HD + hcol;
            float cold = c_state[off];
            float c2 = ff * cold + ii * g2;
            float h2 = oo * tanhfast(c2);
            if (is_enc) {
                int len = lens_s[row];
                if (t >= len) {               // pack_padded semantics
                    c2 = cold;
                    h2 = (float)h_r[off];     // exact fp16 carry
                }
                if (t + 1 == len)             // row's final h (bitwise = R10)
                    hfinal[off] = (_Float16)h2;
            }
            c_state[off] = c2;
            h_w[off] = (_Float16)h2;
        }
    }
}

// Batched outproj: 256 blocks = (8 t) x (32 m-tiles), each 128x128x512.
// Direct-register fragments (no LDS/barriers); perm-scattered output.
__global__ __launch_bounds__(256, 2) void outproj_batch(
    const _Float16* __restrict__ h_slots, int t0,
    const _Float16* __restrict__ Wo, const float* __restrict__ bout,
    const int* __restrict__ perm,
    float* __restrict__ out)
{
    const int tid = threadIdx.x;
    const int lane = tid & 63;
    const int wid  = tid >> 6;
    const int wm    = (wid >> 1) * 64;
    const int wncol = wid & 1;
    const int quad  = lane >> 4;
    const int l15   = lane & 15;

    const int t  = t0 + ((int)blockIdx.x >> 5);
    const int m0 = ((int)blockIdx.x & 31) * 128;
    const _Float16* h_r = h_slots + (size_t)(t % 10) * NBHD;

    const _Float16* arow[4];
    const _Float16* brow[4];
    #pragma unroll
    for (int i = 0; i < 4; i++) {
        arow[i] = h_r + (size_t)(m0 + wm + i * 16 + l15) * HD + quad * 8;
        brow[i] = Wo + (size_t)(wncol * 64 + i * 16 + l15) * HD + quad * 8;
    }

    fx4 acc[4][4];
    #pragma unroll
    for (int i = 0; i < 4; i++)
        #pragma unroll
        for (int jj = 0; jj < 4; jj++)
            acc[i][jj] = fx4{0.f, 0.f, 0.f, 0.f};

    for (int k0 = 0; k0 < HD; k0 += 64) {
        #pragma unroll
        for (int kk = 0; kk < 64; kk += 32) {
            half8 af[4], bf[4];
            #pragma unroll
            for (int mt = 0; mt < 4; mt++)
                af[mt] = *(const half8*)(arow[mt] + k0 + kk);
            #pragma unroll
            for (int nt = 0; nt < 4; nt++)
                bf[nt] = *(const half8*)(brow[nt] + k0 + kk);
            #pragma unroll
            for (int mt = 0; mt < 4; mt++)
                #pragma unroll
                for (int nt = 0; nt < 4; nt++)
                    acc[mt][nt] = __builtin_amdgcn_mfma_f32_16x16x32_f16(
                        af[mt], bf[nt], acc[mt][nt], 0, 0, 0);
        }
    }

    #pragma unroll
    for (int mt = 0; mt < 4; mt++)
        #pragma unroll
        for (int nt = 0; nt < 4; nt++) {
            int v = wncol * 64 + nt * 16 + l15;
            float bo = bout[v];
            #pragma unroll
            for (int r = 0; r < 4; r++) {
                int row = m0 + wm + mt * 16 + quad * 4 + r;   // sorted space
                int orow = perm[row];
                out[((size_t)orow * STGT + t) * NVTGT + v] = acc[mt][nt][r] + bo;
            }
        }
}

extern "C" void kernel_launch(void* const* d_in, const int* in_sizes, int n_in,
                              void* d_out, int out_size, void* d_ws, size_t ws_size,
                              hipStream_t stream) {
    (void)in_sizes; (void)n_in; (void)out_size; (void)ws_size;
    const int* src_seq = (const int*)d_in[0];
    const int* src_len = (const int*)d_in[1];
    const int* tgt_seq = (const int*)d_in[2];
    const float* emb_src = (const float*)d_in[3];
    const float* eWih = (const float*)d_in[4];
    const float* eWhh = (const float*)d_in[5];
    const float* ebih = (const float*)d_in[6];
    const float* ebhh = (const float*)d_in[7];
    const float* emb_tgt = (const float*)d_in[8];
    const float* dWih = (const float*)d_in[9];
    const float* dWhh = (const float*)d_in[10];
    const float* dbih = (const float*)d_in[11];
    const float* dbhh = (const float*)d_in[12];
    const float* Wout = (const float*)d_in[13];
    const float* bout = (const float*)d_in[14];
    float* out = (float*)d_out;

    char* ws = (char*)d_ws;
    size_t off = 0;
    auto carve = [&](size_t bytes) { void* p = ws + off; off += (bytes + 255) & ~(size_t)255; return p; };
    float* proj_src = (float*)carve((size_t)NVSRC * G4 * 4);
    float* proj_tgt = (float*)carve((size_t)NVTGT * G4 * 4);
    float* c_state  = (float*)carve(NBHD * 4);
    _Float16* slots = (_Float16*)carve((size_t)12 * NBHD * 2);   // 48 MB
    _Float16* eW_h  = (_Float16*)carve((size_t)G4 * HD * 2);
    _Float16* dW_h  = (_Float16*)carve((size_t)G4 * HD * 2);
    _Float16* Wo_h  = (_Float16*)carve((size_t)NVTGT * HD * 2);
    _Float16* hfinal = (_Float16*)carve(NBHD * 2);               // 4 MB
    int* perm   = (int*)carve((size_t)NB * 4);
    int* lens_s = (int*)carve((size_t)NB * 4);
    int* maxlen = (int*)carve(32 * 4);
    int* src_s  = (int*)carve((size_t)NB * SSRC * 4);
    int* tgt_s  = (int*)carve((size_t)NB * STGT * 4);
    // WT buffers alias decoder slot 0 (first written at decoder step 0,
    // long after tables are built). 1 MB each, slot is 4 MB.
    float* WT_e = (float*)(slots);
    float* WT_d = (float*)((char*)slots + (size_t)ED * G4 * 4);
    auto slot = [&](int i) { return slots + (size_t)i * NBHD; };

    hipMemsetAsync(c_state, 0, NBHD * 4, stream);

    sort_rows<<<dim3(1), dim3(256), 0, stream>>>(src_len, perm, lens_s, maxlen);
    gather_seq<<<dim3(NB * SSRC / 256), dim3(256), 0, stream>>>(src_seq, perm, src_s);
    gather_seq<<<dim3(NB * STGT / 256), dim3(256), 0, stream>>>(tgt_seq, perm, tgt_s);

    convert_half<<<dim3(G4 * HD / 256), dim3(256), 0, stream>>>(eWhh, G4 * HD, eW_h);
    convert_half<<<dim3(G4 * HD / 256), dim3(256), 0, stream>>>(dWhh, G4 * HD, dW_h);
    convert_half<<<dim3(NVTGT * HD / 256), dim3(256), 0, stream>>>(Wout, NVTGT * HD, Wo_h);
    transpose_f32<<<dim3((G4 / 32) * (ED / 32)), dim3(256), 0, stream>>>(eWih, WT_e, G4, ED, G4 / 32);
    transpose_f32<<<dim3((G4 / 32) * (ED / 32)), dim3(256), 0, stream>>>(dWih, WT_d, G4, ED, G4 / 32);
    build_tables3<<<dim3((NVSRC / 8) * 8), dim3(256), 0, stream>>>(emb_src, WT_e, ebih, ebhh, proj_src);
    build_tables3<<<dim3((NVTGT / 8) * 8), dim3(256), 0, stream>>>(emb_tgt, WT_d, dbih, dbhh, proj_tgt);

    // encoder: slots 10/11 alternate; s=0 skips GEMM (h==0, frozen path
    // never reads h_r at t=0 since len>=1). Finals -> hfinal/c_state.
    for (int s = 0; s < 32; s++) {
        lstm_step<<<dim3(1024), dim3(256), 0, stream>>>(
            slot(10 + (s & 1)), slot(10 + ((s + 1) & 1)), c_state,
            proj_src, src_s, lens_s, maxlen, eW_h, hfinal, s, 1, (s == 0));
    }
    // decoder: 10-slot ring (slot = t mod 10); t=0 reads hfinal.
    for (int t = 0; t < 32; t++) {
        const _Float16* hr = (t == 0) ? hfinal : slot((t - 1) % 10);
        lstm_step<<<dim3(1024), dim3(256), 0, stream>>>(
            hr, slot(t % 10), c_state,
            proj_tgt, tgt_s, lens_s, maxlen, dW_h, hfinal, t, 0, 0);
        if ((t & 7) == 7) {
            outproj_batch<<<dim3(256), dim3(256), 0, stream>>>(
                slots, t - 7, Wo_h, bout, perm, out);
        }
    }
}

// Round 7
// 1439.310 us; speedup vs baseline: 2.4676x; 2.4676x over previous
//
#include <hip/hip_runtime.h>
#include <hip/hip_bf16.h>
#include <hip/hip_fp16.h>
#include <stdint.h>

// Seq2Seq LSTM: B=4096, H=512, E=128, 32 enc + 32 dec steps, V_tgt=128.
// Round 17: CONSOLIDATION on R15 (best, 1458us).
// Ledger: R13 sched micro-opt null; R11/12/14 manual-sync much worse;
// R16 LDS-free much worse (no compiler pipelining, latency-serial).
// R15 work-reduction won. This round, additive safe wins:
//  - epilogue skips c_state write for frozen enc rows (value identical)
//  - decoder ring 16 slots -> outproj = 2 launches x 512 blocks (2/CU)
//  - preamble fused: 1 convert kernel, 1 gather kernel
// Per-cell math identical to R15 -> absmax unchanged.

#define NB     4096
#define SSRC   32
#define STGT   32
#define NVSRC  96
#define NVTGT  128
#define ED     128
#define HD     512
#define G4     2048   // 4*HD
#define NBHD   ((size_t)NB * HD)

typedef __attribute__((ext_vector_type(8))) _Float16 half8;
typedef __attribute__((ext_vector_type(4))) float fx4;

#define AS_G __attribute__((address_space(1)))
#define AS_L __attribute__((address_space(3)))

__device__ __forceinline__ void gl2lds16(const void* g, void* l) {
    // async global->LDS DMA, 16B/lane; LDS dest = wave-uniform base + lane*16
    __builtin_amdgcn_global_load_lds((const AS_G uint32_t*)g, (AS_L uint32_t*)l, 16, 0, 0);
}

__device__ __forceinline__ float sigf(float x) { return 1.0f / (1.0f + __expf(-x)); }
__device__ __forceinline__ float tanhfast(float x) { return 1.0f - 2.0f / (__expf(2.0f * x) + 1.0f); }

// One launch converts eWhh, dWhh, Wout to fp16 (three segments).
__global__ __launch_bounds__(256) void convert_all(
    const float* __restrict__ s1, int n1, _Float16* __restrict__ d1,
    const float* __restrict__ s2, int n2, _Float16* __restrict__ d2,
    const float* __restrict__ s3, int n3, _Float16* __restrict__ d3)
{
    int i = (int)blockIdx.x * 256 + threadIdx.x;
    if (i < n1) { d1[i] = (_Float16)s1[i]; return; }
    i -= n1;
    if (i < n2) { d2[i] = (_Float16)s2[i]; return; }
    i -= n2;
    if (i < n3) d3[i] = (_Float16)s3[i];
}

// 32x32 LDS-tiled transpose: outT[c][r] = in[r][c]; both sides coalesced.
__global__ __launch_bounds__(256) void transpose_f32(
    const float* __restrict__ in, float* __restrict__ outT, int R, int C, int rtiles)
{
    __shared__ float ls[32][33];
    const int bx = (int)blockIdx.x % rtiles;     // r-tile
    const int by = (int)blockIdx.x / rtiles;     // c-tile
    const int tx = threadIdx.x & 31, ty = threadIdx.x >> 5;   // ty 0..7
    #pragma unroll
    for (int i = 0; i < 4; i++) {
        int rr = ty + i * 8;
        ls[rr][tx] = in[(size_t)(bx * 32 + rr) * C + by * 32 + tx];
    }
    __syncthreads();
    #pragma unroll
    for (int i = 0; i < 4; i++) {
        int rr = ty + i * 8;
        outT[(size_t)(by * 32 + rr) * R + bx * 32 + tx] = ls[tx][rr];
    }
}

// proj[v][hcol][gate] = emb[v,:]·Wih[g,:] + bih[g] + bhh[g]  (gate-contig)
// g = gate*HD + hcol in the original gate-major index space.
__global__ __launch_bounds__(256) void build_tables3(
    const float* __restrict__ emb, const float* __restrict__ WT,
    const float* __restrict__ bih, const float* __restrict__ bhh,
    float* __restrict__ proj)
{
    __shared__ float embL[8][ED];
    const int gc = (int)blockIdx.x & 7;
    const int vc = (int)blockIdx.x >> 3;
    const int g  = gc * 256 + threadIdx.x;
    for (int i = threadIdx.x; i < 8 * ED; i += 256)
        embL[i >> 7][i & (ED - 1)] = emb[(size_t)(vc * 8 + (i >> 7)) * ED + (i & (ED - 1))];
    __syncthreads();
    float acc[8] = {0, 0, 0, 0, 0, 0, 0, 0};
    for (int e = 0; e < ED; e++) {
        float w = WT[(size_t)e * G4 + g];
        #pragma unroll
        for (int v = 0; v < 8; v++) acc[v] += embL[v][e] * w;
    }
    float bb = bih[g] + bhh[g];
    const int gate = g >> 9, hcol = g & (HD - 1);
    #pragma unroll
    for (int v = 0; v < 8; v++)
        proj[(((size_t)(vc * 8 + v) * HD + hcol) << 2) + gate] = acc[v] + bb;
}

// Counting sort of rows by src length (keys 1..32). Single block.
__global__ __launch_bounds__(256) void sort_rows(
    const int* __restrict__ lens, int* __restrict__ perm,
    int* __restrict__ lens_s, int* __restrict__ maxlen)
{
    __shared__ int hist[33];
    __shared__ int base[33];
    const int tid = threadIdx.x;
    if (tid < 33) hist[tid] = 0;
    __syncthreads();
    for (int i = tid; i < NB; i += 256) atomicAdd(&hist[lens[i]], 1);
    __syncthreads();
    if (tid == 0) {
        int s = 0;
        for (int l = 1; l <= 32; l++) { base[l] = s; s += hist[l]; }
    }
    __syncthreads();
    for (int i = tid; i < NB; i += 256) {
        int l = lens[i];
        int pos = atomicAdd(&base[l], 1);
        perm[pos] = i;
        lens_s[pos] = l;
    }
    __syncthreads();
    if (tid < 32) maxlen[tid] = lens_s[tid * 128 + 127];
}

// Gathers both src and tgt sequences through perm in one launch.
__global__ __launch_bounds__(256) void gather_seq2(
    const int* __restrict__ src, const int* __restrict__ tgt,
    const int* __restrict__ perm,
    int* __restrict__ src_s, int* __restrict__ tgt_s)
{
    int i = (int)blockIdx.x * 256 + threadIdx.x;   // over 2*NB*32
    int half = i >> 17;                            // NB*32 = 131072 = 1<<17
    int k = i & ((NB * 32) - 1);
    int row = k >> 5, t = k & 31;
    if (half == 0) src_s[k] = src[perm[row] * 32 + t];
    else           tgt_s[k] = tgt[perm[row] * 32 + t];
}

// Gate GEMM, 128m x 64n (4 gates x 16 hcols) per block + fused cell epilogue.
// 1024 blocks = 4 blocks/CU (16 waves/CU). All rows in SORTED space.
__global__ __launch_bounds__(256, 4) void lstm_step(
    const _Float16* __restrict__ h_r, _Float16* __restrict__ h_w,
    float* __restrict__ c_state,
    const float* __restrict__ proj,      // [tok][hcol][4]
    const int* __restrict__ seq_s, const int* __restrict__ lens_s,
    const int* __restrict__ maxlen,
    const _Float16* __restrict__ W,
    _Float16* __restrict__ hfinal,
    int t, int is_enc, int skip_gemm)
{
    __shared__ __align__(16) _Float16 lsA[128 * 64];   // 16 KB
    __shared__ __align__(16) _Float16 lsB[64 * 64];    // 8 KB

    const int tid = threadIdx.x;
    const int lane = tid & 63;
    const int wid  = tid >> 6;
    const int srow = lane >> 3;                    // staging row-in-group
    const int skc  = (((lane & 7) ^ srow)) << 3;   // XOR-swizzled k-chunk
    const int wm   = wid * 32;                     // wave m-offset (0..96)
    const int quad = lane >> 4;
    const int l15  = lane & 15;

    // XCD swizzle: per-XCD ws = 16 m-tiles (2 MB A) + 8 hcol-tiles (0.5 MB B)
    const int x = (int)blockIdx.x & 7, j = (int)blockIdx.x >> 3;
    const int mt = (x & 1) * 16 + (j & 15);            // m-tile (sorted space)
    const int m0 = mt * 128;
    const int c0 = ((x >> 1) * 8 + (j >> 4)) * 16;     // hcol tile (32 total)

    // whole tile frozen: every row already wrote hfinal; c_state holds finals
    if (is_enc && t >= maxlen[mt]) return;

    const _Float16 *ag[4], *bg[2];
    #pragma unroll
    for (int i = 0; i < 4; i++) {
        int lr = wid * 32 + i * 8 + srow;              // local A row 0..127
        ag[i] = h_r + (size_t)(m0 + lr) * HD + skc;
    }
    #pragma unroll
    for (int i = 0; i < 2; i++) {
        int lr = wid * 16 + i * 8 + srow;              // local B row 0..63
        int wr = (lr >> 4) * HD + c0 + (lr & 15);      // gate=lr>>4, tcol=lr&15
        bg[i] = W + (size_t)wr * HD + skc;
    }

    fx4 acc[2][4];
    #pragma unroll
    for (int i = 0; i < 2; i++)
        #pragma unroll
        for (int jj = 0; jj < 4; jj++)
            acc[i][jj] = fx4{0.f, 0.f, 0.f, 0.f};

    if (!skip_gemm) {
        for (int k0 = 0; k0 < HD; k0 += 64) {
            __syncthreads();
            #pragma unroll
            for (int i = 0; i < 4; i++)
                gl2lds16(ag[i] + k0, &lsA[(wid * 32 + i * 8) * 64]);
            #pragma unroll
            for (int i = 0; i < 2; i++)
                gl2lds16(bg[i] + k0, &lsB[(wid * 16 + i * 8) * 64]);
            __syncthreads();
            #pragma unroll
            for (int kk = 0; kk < 64; kk += 32) {
                const int kc = (kk >> 3) + quad;
                half8 af[2], bf[4];
                #pragma unroll
                for (int mf = 0; mf < 2; mf++) {
                    int ar = wm + mf * 16 + l15;
                    int sw = ((kc ^ (ar & 7)) << 3);
                    af[mf] = *(const half8*)&lsA[ar * 64 + sw];
                }
                #pragma unroll
                for (int g = 0; g < 4; g++) {
                    int br = g * 16 + l15;
                    int sw = ((kc ^ (br & 7)) << 3);
                    bf[g] = *(const half8*)&lsB[br * 64 + sw];
                }
                #pragma unroll
                for (int mf = 0; mf < 2; mf++)
                    #pragma unroll
                    for (int g = 0; g < 4; g++)
                        acc[mf][g] = __builtin_amdgcn_mfma_f32_16x16x32_f16(af[mf], bf[g], acc[mf][g], 0, 0, 0);
            }
        }
    }

    // fused cell epilogue: acc[mf][gate][r] — all 4 gates per (row,hcol)
    const int hcol = c0 + l15;
    #pragma unroll
    for (int mf = 0; mf < 2; mf++) {
        #pragma unroll
        for (int r = 0; r < 4; r++) {
            int row = m0 + wm + mf * 16 + quad * 4 + r;
            int tok = is_enc ? seq_s[row * SSRC + t]
                             : (t == 0 ? 1 : seq_s[row * STGT + t - 1]);  // SOS=1
            const fx4 xp = *(const fx4*)&proj[((size_t)tok * HD + hcol) << 2];
            float gi = acc[mf][0][r] + xp[0];
            float gf = acc[mf][1][r] + xp[1];
            float gg = acc[mf][2][r] + xp[2];
            float go = acc[mf][3][r] + xp[3];
            float ii = sigf(gi), ff = sigf(gf), oo = sigf(go);
            float g2 = tanhfast(gg);
            size_t off = (size_t)row * HD + hcol;
            float cold = c_state[off];
            float c2 = ff * cold + ii * g2;
            float h2 = oo * tanhfast(c2);
            bool cwrite = true;
            if (is_enc) {
                int len = lens_s[row];
                if (t >= len) {               // pack_padded semantics
                    c2 = cold;
                    cwrite = false;           // value identical -> skip write
                    h2 = (float)h_r[off];     // exact fp16 carry
                }
                if (t + 1 == len)             // row's final h (bitwise = R10)
                    hfinal[off] = (_Float16)h2;
            }
            if (cwrite) c_state[off] = c2;
            h_w[off] = (_Float16)h2;
        }
    }
}

// Batched outproj: 512 blocks = (16 t) x (32 m-tiles), each 128x128x512.
// 2 blocks/CU exact fill. Rows in sorted space; scatter via perm.
__global__ __launch_bounds__(256, 2) void outproj_batch(
    const _Float16* __restrict__ h_slots, int t0,
    const _Float16* __restrict__ Wo, const float* __restrict__ bout,
    const int* __restrict__ perm,
    float* __restrict__ out)
{
    __shared__ __align__(16) _Float16 lsA[128 * 64];
    __shared__ __align__(16) _Float16 lsB[128 * 64];

    const int tid = threadIdx.x;
    const int lane = tid & 63;
    const int wid  = tid >> 6;
    const int srow = lane >> 3;
    const int skc  = (((lane & 7) ^ srow)) << 3;
    const int wm    = (wid >> 1) * 64;
    const int wncol = wid & 1;
    const int quad  = lane >> 4;
    const int l15   = lane & 15;
    const int bsw   = (l15 & 7);

    const int t  = t0 + ((int)blockIdx.x >> 5);        // 16 t per launch
    const int m0 = ((int)blockIdx.x & 31) * 128;
    const _Float16* h_r = h_slots + (size_t)(t & 15) * NBHD;   // ring-16

    const _Float16 *ag[4], *bg[4];
    #pragma unroll
    for (int i = 0; i < 4; i++) {
        int lr = wid * 32 + i * 8 + srow;
        ag[i] = h_r + (size_t)(m0 + lr) * HD + skc;
        bg[i] = Wo + (size_t)lr * HD + skc;   // Wout row = v
    }

    fx4 acc[4][4];
    #pragma unroll
    for (int i = 0; i < 4; i++)
        #pragma unroll
        for (int jj = 0; jj < 4; jj++)
            acc[i][jj] = fx4{0.f, 0.f, 0.f, 0.f};

    for (int k0 = 0; k0 < HD; k0 += 64) {
        __syncthreads();
        #pragma unroll
        for (int i = 0; i < 4; i++) {
            int lb = (wid * 32 + i * 8) * 64;
            gl2lds16(ag[i] + k0, &lsA[lb]);
            gl2lds16(bg[i] + k0, &lsB[lb]);
        }
        __syncthreads();
        #pragma unroll
        for (int kk = 0; kk < 64; kk += 32) {
            const int kc = (kk >> 3) + quad;
            const int sw = ((kc ^ bsw) << 3);
            half8 af[4], bf[4];
            #pragma unroll
            for (int mt = 0; mt < 4; mt++)
                af[mt] = *(const half8*)&lsA[(wm + mt * 16 + l15) * 64 + sw];
            #pragma unroll
            for (int nt = 0; nt < 4; nt++)
                bf[nt] = *(const half8*)&lsB[(wncol * 64 + nt * 16 + l15) * 64 + sw];
            #pragma unroll
            for (int mt = 0; mt < 4; mt++)
                #pragma unroll
                for (int nt = 0; nt < 4; nt++)
                    acc[mt][nt] = __builtin_amdgcn_mfma_f32_16x16x32_f16(af[mt], bf[nt], acc[mt][nt], 0, 0, 0);
        }
    }

    #pragma unroll
    for (int mt = 0; mt < 4; mt++)
        #pragma unroll
        for (int nt = 0; nt < 4; nt++) {
            int v = wncol * 64 + nt * 16 + l15;
            float bo = bout[v];
            #pragma unroll
            for (int r = 0; r < 4; r++) {
                int row = m0 + wm + mt * 16 + quad * 4 + r;   // sorted space
                int orow = perm[row];
                out[((size_t)orow * STGT + t) * NVTGT + v] = acc[mt][nt][r] + bo;
            }
        }
}

extern "C" void kernel_launch(void* const* d_in, const int* in_sizes, int n_in,
                              void* d_out, int out_size, void* d_ws, size_t ws_size,
                              hipStream_t stream) {
    (void)in_sizes; (void)n_in; (void)out_size; (void)ws_size;
    const int* src_seq = (const int*)d_in[0];
    const int* src_len = (const int*)d_in[1];
    const int* tgt_seq = (const int*)d_in[2];
    const float* emb_src = (const float*)d_in[3];
    const float* eWih = (const float*)d_in[4];
    const float* eWhh = (const float*)d_in[5];
    const float* ebih = (const float*)d_in[6];
    const float* ebhh = (const float*)d_in[7];
    const float* emb_tgt = (const float*)d_in[8];
    const float* dWih = (const float*)d_in[9];
    const float* dWhh = (const float*)d_in[10];
    const float* dbih = (const float*)d_in[11];
    const float* dbhh = (const float*)d_in[12];
    const float* Wout = (const float*)d_in[13];
    const float* bout = (const float*)d_in[14];
    float* out = (float*)d_out;

    char* ws = (char*)d_ws;
    size_t off = 0;
    auto carve = [&](size_t bytes) { void* p = ws + off; off += (bytes + 255) & ~(size_t)255; return p; };
    float* proj_src = (float*)carve((size_t)NVSRC * G4 * 4);
    float* proj_tgt = (float*)carve((size_t)NVTGT * G4 * 4);
    float* c_state  = (float*)carve(NBHD * 4);
    _Float16* slots = (_Float16*)carve((size_t)18 * NBHD * 2);   // 72 MB
    _Float16* eW_h  = (_Float16*)carve((size_t)G4 * HD * 2);
    _Float16* dW_h  = (_Float16*)carve((size_t)G4 * HD * 2);
    _Float16* Wo_h  = (_Float16*)carve((size_t)NVTGT * HD * 2);
    _Float16* hfinal = (_Float16*)carve(NBHD * 2);               // 4 MB
    int* perm   = (int*)carve((size_t)NB * 4);
    int* lens_s = (int*)carve((size_t)NB * 4);
    int* maxlen = (int*)carve(32 * 4);
    int* src_s  = (int*)carve((size_t)NB * SSRC * 4);
    int* tgt_s  = (int*)carve((size_t)NB * STGT * 4);
    // WT buffers alias decoder slot 0 (first written at decoder step 0,
    // long after tables are built). 1 MB each, slot is 4 MB.
    float* WT_e = (float*)(slots);
    float* WT_d = (float*)((char*)slots + (size_t)ED * G4 * 4);
    auto slot = [&](int i) { return slots + (size_t)i * NBHD; };

    hipMemsetAsync(c_state, 0, NBHD * 4, stream);

    sort_rows<<<dim3(1), dim3(256), 0, stream>>>(src_len, perm, lens_s, maxlen);
    gather_seq2<<<dim3(2 * NB * SSRC / 256), dim3(256), 0, stream>>>(
        src_seq, tgt_seq, perm, src_s, tgt_s);

    {
        int n1 = G4 * HD, n2 = G4 * HD, n3 = NVTGT * HD;
        int nb = (n1 + n2 + n3 + 255) / 256;
        convert_all<<<dim3(nb), dim3(256), 0, stream>>>(
            eWhh, n1, eW_h, dWhh, n2, dW_h, Wout, n3, Wo_h);
    }
    transpose_f32<<<dim3((G4 / 32) * (ED / 32)), dim3(256), 0, stream>>>(eWih, WT_e, G4, ED, G4 / 32);
    transpose_f32<<<dim3((G4 / 32) * (ED / 32)), dim3(256), 0, stream>>>(dWih, WT_d, G4, ED, G4 / 32);
    build_tables3<<<dim3((NVSRC / 8) * 8), dim3(256), 0, stream>>>(emb_src, WT_e, ebih, ebhh, proj_src);
    build_tables3<<<dim3((NVTGT / 8) * 8), dim3(256), 0, stream>>>(emb_tgt, WT_d, dbih, dbhh, proj_tgt);

    // encoder: slots 16/17 alternate; s=0 skips GEMM (h==0; frozen path
    // never taken at t=0 since len>=1). Finals -> hfinal/c_state.
    for (int s = 0; s < 32; s++) {
        lstm_step<<<dim3(1024), dim3(256), 0, stream>>>(
            slot(16 + (s & 1)), slot(16 + ((s + 1) & 1)), c_state,
            proj_src, src_s, lens_s, maxlen, eW_h, hfinal, s, 1, (s == 0));
    }
    // decoder: 16-slot ring (slot = t mod 16); t=0 reads hfinal.
    // outproj after t=15 and t=31 (512 blocks, 16 timesteps each).
    for (int t = 0; t < 32; t++) {
        const _Float16* hr = (t == 0) ? hfinal : slot((t - 1) & 15);
        lstm_step<<<dim3(1024), dim3(256), 0, stream>>>(
            hr, slot(t & 15), c_state,
            proj_tgt, tgt_s, lens_s, maxlen, dW_h, hfinal, t, 0, 0);
        if ((t & 15) == 15) {
            outproj_batch<<<dim3(512), dim3(256), 0, stream>>>(
                slots, t - 15, Wo_h, bout, perm, out);
        }
    }
}

// Round 8
// 1369.701 us; speedup vs baseline: 2.5931x; 1.0508x over previous
//
#include <hip/hip_runtime.h>
#include <hip/hip_bf16.h>
#include <hip/hip_fp16.h>
#include <stdint.h>

// Seq2Seq LSTM: B=4096, H=512, E=128, 32 enc + 32 dec steps, V_tgt=128.
// Round 18: FAT 128x128 TILES for lstm_step (A-multicast halved).
// Ledger: R13 sched micro-opt null; R11/12/14 manual-sync much worse; R16
// LDS-free much worse; R15/R17 work-reduction + consolidation won.
// This round: 512 blocks = 32m x 16c tiles, 512 threads (8 waves). Wave =
// 32m x 64n = 2 m-frags x 4 n-frags (n-frag == gate at a 16-hcol group) —
// identical per-wave MFMA stream, identical fused epilogue per cell.
// Occupancy unchanged: 2 blocks x 8 waves = 16 waves/CU (launch_bounds
// (512,4) = 4 waves/SIMD). A read 16x instead of 32x: GEMM traffic
// 192 -> 128 MB/step; staging instructions -33%; 512 vs 1024 dispatches.
// Keeps R17: enc early-exit, frozen-row c-write skip, float4 proj, ring-16
// decoder + 2 outproj launches, fused preamble. absmax unchanged.

#define NB     4096
#define SSRC   32
#define STGT   32
#define NVSRC  96
#define NVTGT  128
#define ED     128
#define HD     512
#define G4     2048   // 4*HD
#define NBHD   ((size_t)NB * HD)

typedef __attribute__((ext_vector_type(8))) _Float16 half8;
typedef __attribute__((ext_vector_type(4))) float fx4;

#define AS_G __attribute__((address_space(1)))
#define AS_L __attribute__((address_space(3)))

__device__ __forceinline__ void gl2lds16(const void* g, void* l) {
    // async global->LDS DMA, 16B/lane; LDS dest = wave-uniform base + lane*16
    __builtin_amdgcn_global_load_lds((const AS_G uint32_t*)g, (AS_L uint32_t*)l, 16, 0, 0);
}

__device__ __forceinline__ float sigf(float x) { return 1.0f / (1.0f + __expf(-x)); }
__device__ __forceinline__ float tanhfast(float x) { return 1.0f - 2.0f / (__expf(2.0f * x) + 1.0f); }

// One launch converts eWhh, dWhh, Wout to fp16 (three segments).
__global__ __launch_bounds__(256) void convert_all(
    const float* __restrict__ s1, int n1, _Float16* __restrict__ d1,
    const float* __restrict__ s2, int n2, _Float16* __restrict__ d2,
    const float* __restrict__ s3, int n3, _Float16* __restrict__ d3)
{
    int i = (int)blockIdx.x * 256 + threadIdx.x;
    if (i < n1) { d1[i] = (_Float16)s1[i]; return; }
    i -= n1;
    if (i < n2) { d2[i] = (_Float16)s2[i]; return; }
    i -= n2;
    if (i < n3) d3[i] = (_Float16)s3[i];
}

// 32x32 LDS-tiled transpose: outT[c][r] = in[r][c]; both sides coalesced.
__global__ __launch_bounds__(256) void transpose_f32(
    const float* __restrict__ in, float* __restrict__ outT, int R, int C, int rtiles)
{
    __shared__ float ls[32][33];
    const int bx = (int)blockIdx.x % rtiles;     // r-tile
    const int by = (int)blockIdx.x / rtiles;     // c-tile
    const int tx = threadIdx.x & 31, ty = threadIdx.x >> 5;   // ty 0..7
    #pragma unroll
    for (int i = 0; i < 4; i++) {
        int rr = ty + i * 8;
        ls[rr][tx] = in[(size_t)(bx * 32 + rr) * C + by * 32 + tx];
    }
    __syncthreads();
    #pragma unroll
    for (int i = 0; i < 4; i++) {
        int rr = ty + i * 8;
        outT[(size_t)(by * 32 + rr) * R + bx * 32 + tx] = ls[tx][rr];
    }
}

// proj[v][hcol][gate] = emb[v,:]·Wih[g,:] + bih[g] + bhh[g]  (gate-contig)
// g = gate*HD + hcol in the original gate-major index space.
__global__ __launch_bounds__(256) void build_tables3(
    const float* __restrict__ emb, const float* __restrict__ WT,
    const float* __restrict__ bih, const float* __restrict__ bhh,
    float* __restrict__ proj)
{
    __shared__ float embL[8][ED];
    const int gc = (int)blockIdx.x & 7;
    const int vc = (int)blockIdx.x >> 3;
    const int g  = gc * 256 + threadIdx.x;
    for (int i = threadIdx.x; i < 8 * ED; i += 256)
        embL[i >> 7][i & (ED - 1)] = emb[(size_t)(vc * 8 + (i >> 7)) * ED + (i & (ED - 1))];
    __syncthreads();
    float acc[8] = {0, 0, 0, 0, 0, 0, 0, 0};
    for (int e = 0; e < ED; e++) {
        float w = WT[(size_t)e * G4 + g];
        #pragma unroll
        for (int v = 0; v < 8; v++) acc[v] += embL[v][e] * w;
    }
    float bb = bih[g] + bhh[g];
    const int gate = g >> 9, hcol = g & (HD - 1);
    #pragma unroll
    for (int v = 0; v < 8; v++)
        proj[(((size_t)(vc * 8 + v) * HD + hcol) << 2) + gate] = acc[v] + bb;
}

// Counting sort of rows by src length (keys 1..32). Single block.
__global__ __launch_bounds__(256) void sort_rows(
    const int* __restrict__ lens, int* __restrict__ perm,
    int* __restrict__ lens_s, int* __restrict__ maxlen)
{
    __shared__ int hist[33];
    __shared__ int base[33];
    const int tid = threadIdx.x;
    if (tid < 33) hist[tid] = 0;
    __syncthreads();
    for (int i = tid; i < NB; i += 256) atomicAdd(&hist[lens[i]], 1);
    __syncthreads();
    if (tid == 0) {
        int s = 0;
        for (int l = 1; l <= 32; l++) { base[l] = s; s += hist[l]; }
    }
    __syncthreads();
    for (int i = tid; i < NB; i += 256) {
        int l = lens[i];
        int pos = atomicAdd(&base[l], 1);
        perm[pos] = i;
        lens_s[pos] = l;
    }
    __syncthreads();
    if (tid < 32) maxlen[tid] = lens_s[tid * 128 + 127];
}

// Gathers both src and tgt sequences through perm in one launch.
__global__ __launch_bounds__(256) void gather_seq2(
    const int* __restrict__ src, const int* __restrict__ tgt,
    const int* __restrict__ perm,
    int* __restrict__ src_s, int* __restrict__ tgt_s)
{
    int i = (int)blockIdx.x * 256 + threadIdx.x;   // over 2*NB*32
    int half = i >> 17;                            // NB*32 = 131072 = 1<<17
    int k = i & ((NB * 32) - 1);
    int row = k >> 5, t = k & 31;
    if (half == 0) src_s[k] = src[perm[row] * 32 + t];
    else           tgt_s[k] = tgt[perm[row] * 32 + t];
}

// Gate GEMM, 128m x 128n (4 gates x 32 hcols) per block + fused epilogue.
// 512 blocks x 512 threads (8 waves): 2 blocks/CU = 16 waves/CU (same as
// R17's 4x4). Wave = 32m x 64n: 2 m-frags x 4 n-frags, n-frag == gate at
// hcol group hgrp=(wid>>2)*16 -> each lane owns all 4 gates per (row,hcol).
__global__ __launch_bounds__(512, 4) void lstm_step(
    const _Float16* __restrict__ h_r, _Float16* __restrict__ h_w,
    float* __restrict__ c_state,
    const float* __restrict__ proj,      // [tok][hcol][4]
    const int* __restrict__ seq_s, const int* __restrict__ lens_s,
    const int* __restrict__ maxlen,
    const _Float16* __restrict__ W,
    _Float16* __restrict__ hfinal,
    int t, int is_enc, int skip_gemm)
{
    __shared__ __align__(16) _Float16 lsA[128 * 64];   // 16 KB
    __shared__ __align__(16) _Float16 lsB[128 * 64];   // 16 KB

    const int tid = threadIdx.x;
    const int lane = tid & 63;
    const int wid  = tid >> 6;                     // 0..7
    const int srow = lane >> 3;                    // staging row-in-group
    const int skc  = (((lane & 7) ^ srow)) << 3;   // XOR-swizzled k-chunk
    const int wm   = (wid & 3) * 32;               // wave m-offset (0..96)
    const int hgrp = (wid >> 2) * 16;              // hcol 16-group in c-tile
    const int quad = lane >> 4;
    const int l15  = lane & 15;

    // XCD swizzle: per-XCD ws = 16 m-tiles + 4 c-tiles
    const int x = (int)blockIdx.x & 7, j = (int)blockIdx.x >> 3;
    const int mt = (x & 1) * 16 + (j & 15);            // m-tile (sorted space)
    const int m0 = mt * 128;
    const int c0 = ((x >> 1) * 4 + (j >> 4)) * 32;     // hcol tile (16 total)

    // whole tile frozen: every row already wrote hfinal; c_state holds finals
    if (is_enc && t >= maxlen[mt]) return;

    const _Float16 *ag[2], *bg[2];
    #pragma unroll
    for (int i = 0; i < 2; i++) {
        int lr = wid * 16 + i * 8 + srow;              // local row 0..127
        ag[i] = h_r + (size_t)(m0 + lr) * HD + skc;
        // B row lr -> (gate = lr>>5, hc = lr&31)
        int wr = (lr >> 5) * HD + c0 + (lr & 31);
        bg[i] = W + (size_t)wr * HD + skc;
    }

    fx4 acc[2][4];
    #pragma unroll
    for (int i = 0; i < 2; i++)
        #pragma unroll
        for (int jj = 0; jj < 4; jj++)
            acc[i][jj] = fx4{0.f, 0.f, 0.f, 0.f};

    if (!skip_gemm) {
        for (int k0 = 0; k0 < HD; k0 += 64) {
            __syncthreads();
            #pragma unroll
            for (int i = 0; i < 2; i++) {
                gl2lds16(ag[i] + k0, &lsA[(wid * 16 + i * 8) * 64]);
                gl2lds16(bg[i] + k0, &lsB[(wid * 16 + i * 8) * 64]);
            }
            __syncthreads();
            #pragma unroll
            for (int kk = 0; kk < 64; kk += 32) {
                const int kc = (kk >> 3) + quad;
                half8 af[2], bf[4];
                #pragma unroll
                for (int mf = 0; mf < 2; mf++) {
                    int ar = wm + mf * 16 + l15;
                    int sw = ((kc ^ (ar & 7)) << 3);
                    af[mf] = *(const half8*)&lsA[ar * 64 + sw];
                }
                #pragma unroll
                for (int g = 0; g < 4; g++) {
                    int br = g * 32 + hgrp + l15;
                    int sw = ((kc ^ (br & 7)) << 3);
                    bf[g] = *(const half8*)&lsB[br * 64 + sw];
                }
                #pragma unroll
                for (int mf = 0; mf < 2; mf++)
                    #pragma unroll
                    for (int g = 0; g < 4; g++)
                        acc[mf][g] = __builtin_amdgcn_mfma_f32_16x16x32_f16(af[mf], bf[g], acc[mf][g], 0, 0, 0);
            }
        }
    }

    // fused cell epilogue: acc[mf][gate][r] — all 4 gates per (row,hcol)
    const int hcol = c0 + hgrp + l15;
    #pragma unroll
    for (int mf = 0; mf < 2; mf++) {
        #pragma unroll
        for (int r = 0; r < 4; r++) {
            int row = m0 + wm + mf * 16 + quad * 4 + r;
            int tok = is_enc ? seq_s[row * SSRC + t]
                             : (t == 0 ? 1 : seq_s[row * STGT + t - 1]);  // SOS=1
            const fx4 xp = *(const fx4*)&proj[((size_t)tok * HD + hcol) << 2];
            float gi = acc[mf][0][r] + xp[0];
            float gf = acc[mf][1][r] + xp[1];
            float gg = acc[mf][2][r] + xp[2];
            float go = acc[mf][3][r] + xp[3];
            float ii = sigf(gi), ff = sigf(gf), oo = sigf(go);
            float g2 = tanhfast(gg);
            size_t off = (size_t)row * HD + hcol;
            float cold = c_state[off];
            float c2 = ff * cold + ii * g2;
            float h2 = oo * tanhfast(c2);
            bool cwrite = true;
            if (is_enc) {
                int len = lens_s[row];
                if (t >= len) {               // pack_padded semantics
                    c2 = cold;
                    cwrite = false;           // value identical -> skip write
                    h2 = (float)h_r[off];     // exact fp16 carry
                }
                if (t + 1 == len)             // row's final h (bitwise = R10)
                    hfinal[off] = (_Float16)h2;
            }
            if (cwrite) c_state[off] = c2;
            h_w[off] = (_Float16)h2;
        }
    }
}

// Batched outproj: 512 blocks = (16 t) x (32 m-tiles), each 128x128x512.
// 2 blocks/CU exact fill. Rows in sorted space; scatter via perm.
__global__ __launch_bounds__(256, 2) void outproj_batch(
    const _Float16* __restrict__ h_slots, int t0,
    const _Float16* __restrict__ Wo, const float* __restrict__ bout,
    const int* __restrict__ perm,
    float* __restrict__ out)
{
    __shared__ __align__(16) _Float16 lsA[128 * 64];
    __shared__ __align__(16) _Float16 lsB[128 * 64];

    const int tid = threadIdx.x;
    const int lane = tid & 63;
    const int wid  = tid >> 6;
    const int srow = lane >> 3;
    const int skc  = (((lane & 7) ^ srow)) << 3;
    const int wm    = (wid >> 1) * 64;
    const int wncol = wid & 1;
    const int quad  = lane >> 4;
    const int l15   = lane & 15;
    const int bsw   = (l15 & 7);

    const int t  = t0 + ((int)blockIdx.x >> 5);        // 16 t per launch
    const int m0 = ((int)blockIdx.x & 31) * 128;
    const _Float16* h_r = h_slots + (size_t)(t & 15) * NBHD;   // ring-16

    const _Float16 *ag[4], *bg[4];
    #pragma unroll
    for (int i = 0; i < 4; i++) {
        int lr = wid * 32 + i * 8 + srow;
        ag[i] = h_r + (size_t)(m0 + lr) * HD + skc;
        bg[i] = Wo + (size_t)lr * HD + skc;   // Wout row = v
    }

    fx4 acc[4][4];
    #pragma unroll
    for (int i = 0; i < 4; i++)
        #pragma unroll
        for (int jj = 0; jj < 4; jj++)
            acc[i][jj] = fx4{0.f, 0.f, 0.f, 0.f};

    for (int k0 = 0; k0 < HD; k0 += 64) {
        __syncthreads();
        #pragma unroll
        for (int i = 0; i < 4; i++) {
            int lb = (wid * 32 + i * 8) * 64;
            gl2lds16(ag[i] + k0, &lsA[lb]);
            gl2lds16(bg[i] + k0, &lsB[lb]);
        }
        __syncthreads();
        #pragma unroll
        for (int kk = 0; kk < 64; kk += 32) {
            const int kc = (kk >> 3) + quad;
            const int sw = ((kc ^ bsw) << 3);
            half8 af[4], bf[4];
            #pragma unroll
            for (int mt = 0; mt < 4; mt++)
                af[mt] = *(const half8*)&lsA[(wm + mt * 16 + l15) * 64 + sw];
            #pragma unroll
            for (int nt = 0; nt < 4; nt++)
                bf[nt] = *(const half8*)&lsB[(wncol * 64 + nt * 16 + l15) * 64 + sw];
            #pragma unroll
            for (int mt = 0; mt < 4; mt++)
                #pragma unroll
                for (int nt = 0; nt < 4; nt++)
                    acc[mt][nt] = __builtin_amdgcn_mfma_f32_16x16x32_f16(af[mt], bf[nt], acc[mt][nt], 0, 0, 0);
        }
    }

    #pragma unroll
    for (int mt = 0; mt < 4; mt++)
        #pragma unroll
        for (int nt = 0; nt < 4; nt++) {
            int v = wncol * 64 + nt * 16 + l15;
            float bo = bout[v];
            #pragma unroll
            for (int r = 0; r < 4; r++) {
                int row = m0 + wm + mt * 16 + quad * 4 + r;   // sorted space
                int orow = perm[row];
                out[((size_t)orow * STGT + t) * NVTGT + v] = acc[mt][nt][r] + bo;
            }
        }
}

extern "C" void kernel_launch(void* const* d_in, const int* in_sizes, int n_in,
                              void* d_out, int out_size, void* d_ws, size_t ws_size,
                              hipStream_t stream) {
    (void)in_sizes; (void)n_in; (void)out_size; (void)ws_size;
    const int* src_seq = (const int*)d_in[0];
    const int* src_len = (const int*)d_in[1];
    const int* tgt_seq = (const int*)d_in[2];
    const float* emb_src = (const float*)d_in[3];
    const float* eWih = (const float*)d_in[4];
    const float* eWhh = (const float*)d_in[5];
    const float* ebih = (const float*)d_in[6];
    const float* ebhh = (const float*)d_in[7];
    const float* emb_tgt = (const float*)d_in[8];
    const float* dWih = (const float*)d_in[9];
    const float* dWhh = (const float*)d_in[10];
    const float* dbih = (const float*)d_in[11];
    const float* dbhh = (const float*)d_in[12];
    const float* Wout = (const float*)d_in[13];
    const float* bout = (const float*)d_in[14];
    float* out = (float*)d_out;

    char* ws = (char*)d_ws;
    size_t off = 0;
    auto carve = [&](size_t bytes) { void* p = ws + off; off += (bytes + 255) & ~(size_t)255; return p; };
    float* proj_src = (float*)carve((size_t)NVSRC * G4 * 4);
    float* proj_tgt = (float*)carve((size_t)NVTGT * G4 * 4);
    float* c_state  = (float*)carve(NBHD * 4);
    _Float16* slots = (_Float16*)carve((size_t)18 * NBHD * 2);   // 72 MB
    _Float16* eW_h  = (_Float16*)carve((size_t)G4 * HD * 2);
    _Float16* dW_h  = (_Float16*)carve((size_t)G4 * HD * 2);
    _Float16* Wo_h  = (_Float16*)carve((size_t)NVTGT * HD * 2);
    _Float16* hfinal = (_Float16*)carve(NBHD * 2);               // 4 MB
    int* perm   = (int*)carve((size_t)NB * 4);
    int* lens_s = (int*)carve((size_t)NB * 4);
    int* maxlen = (int*)carve(32 * 4);
    int* src_s  = (int*)carve((size_t)NB * SSRC * 4);
    int* tgt_s  = (int*)carve((size_t)NB * STGT * 4);
    // WT buffers alias decoder slot 0 (first written at decoder step 0,
    // long after tables are built). 1 MB each, slot is 4 MB.
    float* WT_e = (float*)(slots);
    float* WT_d = (float*)((char*)slots + (size_t)ED * G4 * 4);
    auto slot = [&](int i) { return slots + (size_t)i * NBHD; };

    hipMemsetAsync(c_state, 0, NBHD * 4, stream);

    sort_rows<<<dim3(1), dim3(256), 0, stream>>>(src_len, perm, lens_s, maxlen);
    gather_seq2<<<dim3(2 * NB * SSRC / 256), dim3(256), 0, stream>>>(
        src_seq, tgt_seq, perm, src_s, tgt_s);

    {
        int n1 = G4 * HD, n2 = G4 * HD, n3 = NVTGT * HD;
        int nb = (n1 + n2 + n3 + 255) / 256;
        convert_all<<<dim3(nb), dim3(256), 0, stream>>>(
            eWhh, n1, eW_h, dWhh, n2, dW_h, Wout, n3, Wo_h);
    }
    transpose_f32<<<dim3((G4 / 32) * (ED / 32)), dim3(256), 0, stream>>>(eWih, WT_e, G4, ED, G4 / 32);
    transpose_f32<<<dim3((G4 / 32) * (ED / 32)), dim3(256), 0, stream>>>(dWih, WT_d, G4, ED, G4 / 32);
    build_tables3<<<dim3((NVSRC / 8) * 8), dim3(256), 0, stream>>>(emb_src, WT_e, ebih, ebhh, proj_src);
    build_tables3<<<dim3((NVTGT / 8) * 8), dim3(256), 0, stream>>>(emb_tgt, WT_d, dbih, dbhh, proj_tgt);

    // encoder: slots 16/17 alternate; s=0 skips GEMM (h==0; frozen path
    // never taken at t=0 since len>=1). Finals -> hfinal/c_state.
    for (int s = 0; s < 32; s++) {
        lstm_step<<<dim3(512), dim3(512), 0, stream>>>(
            slot(16 + (s & 1)), slot(16 + ((s + 1) & 1)), c_state,
            proj_src, src_s, lens_s, maxlen, eW_h, hfinal, s, 1, (s == 0));
    }
    // decoder: 16-slot ring (slot = t mod 16); t=0 reads hfinal.
    // outproj after t=15 and t=31 (512 blocks, 16 timesteps each).
    for (int t = 0; t < 32; t++) {
        const _Float16* hr = (t == 0) ? hfinal : slot((t - 1) & 15);
        lstm_step<<<dim3(512), dim3(512), 0, stream>>>(
            hr, slot(t & 15), c_state,
            proj_tgt, tgt_s, lens_s, maxlen, dW_h, hfinal, t, 0, 0);
        if ((t & 15) == 15) {
            outproj_batch<<<dim3(512), dim3(256), 0, stream>>>(
                slots, t - 15, Wo_h, bout, perm, out);
        }
    }
}